// Round 13
// baseline (35.643 us; speedup 1.0000x reference)
//
#include <hip/hip_runtime.h>

constexpr int K  = 3;
constexpr int Hc = 512, Wc = 512, Bc = 8;
constexpr int HWc = Hc * Wc;
constexpr int LROW = Wc + 4;          // 516 floats per LDS row (cols -1..514)
constexpr int LTOT = 5 * LROW;        // 5 staged rows

typedef __attribute__((ext_vector_type(2))) unsigned int u32x2;
typedef __attribute__((ext_vector_type(4))) unsigned int u32x4;

__device__ __forceinline__ float bl32(__amdgpu_buffer_rsrc_t r, int vo, int so) {
    return __uint_as_float(__builtin_amdgcn_raw_buffer_load_b32(r, vo, so, 0));
}
__device__ __forceinline__ u32x4 bl128(__amdgpu_buffer_rsrc_t r, int vo, int so) {
    return __builtin_amdgcn_raw_buffer_load_b128(r, vo, so, 0);
}
__device__ __forceinline__ unsigned umax2(unsigned a, unsigned b) { return a > b ? a : b; }
__device__ __forceinline__ float elem(u32x4 v, int j) {
    return __uint_as_float(j == 0 ? v.x : j == 1 ? v.y : j == 2 ? v.z : v.w);
}

__global__ __launch_bounds__(256, 6) void deform_conv2d_kernel(
    const float* __restrict__ inp,     // (B,H,W)
    const float* __restrict__ wgt,     // (K*K)
    const float* __restrict__ off,     // (B, 2*K*K, H, W)
    float* __restrict__ out)           // (B,H,W)
{
    __shared__ float lds[LTOT];

    // block covers 2 consecutive rows (1024 px) of one batch image
    const int bid = blockIdx.x;
    const int b   = bid >> 8;            // / 256 row-pairs
    const int h0  = (bid & 255) << 1;
    const int t   = threadIdx.x;
    const int rloc = (t * 4) >> 9;       // 0 or 1
    const int w    = (t * 4) & (Wc - 1); // multiple of 4
    const int h    = h0 + rloc;
    const int hw   = h * Wc + w;

    __amdgpu_buffer_rsrc_t orsrc = __builtin_amdgcn_make_buffer_rsrc(
        (void*)(off + (size_t)b * (2 * K * K) * HWc), (short)0,
        (2 * K * K) * HWc * 4, 0x00020000);
    __amdgpu_buffer_rsrc_t irsrc = __builtin_amdgcn_make_buffer_rsrc(
        (void*)(inp + (size_t)b * HWc), (short)0, HWc * 4, 0x00020000);

    // ---- stage 5 zero-padded image rows (h0-1 .. h0+3, cols -1..514) ----
    // Row OOB free via SRD bounds check (negative/overflow voffset -> 0).
    // Col OOB (-1, 512..514) masked explicitly (those addrs alias other rows).
#pragma unroll
    for (int i = 0; i < 11; ++i) {
        const int s = i * 256 + t;
        if (s < LTOT) {
            const int row  = s / LROW;            // magic-mul div
            const int col  = s - row * LROW - 1;  // image col
            const int grow = h0 - 1 + row;
            const float v  = bl32(irsrc, (grow * Wc + col) * 4, 0);
            lds[s] = ((unsigned)col < (unsigned)Wc) ? v : 0.f;
        }
    }
    __syncthreads();

    // ---- copy this thread's 4x7 window LDS -> registers (conflict-free b128) ----
    float win[4][7];
#pragma unroll
    for (int r = 0; r < 4; ++r) {
        const int base = (rloc + r) * LROW + w;   // slot of image col w-1; 16B aligned
        const float4 lo = *reinterpret_cast<const float4*>(&lds[base]);
        const float4 hi = *reinterpret_cast<const float4*>(&lds[base + 4]);
        win[r][0] = lo.x; win[r][1] = lo.y; win[r][2] = lo.z; win[r][3] = lo.w;
        win[r][4] = hi.x; win[r][5] = hi.y; win[r][6] = hi.z;
    }

    const int hwB = hw * 4;
    float acc[4] = {0.f, 0.f, 0.f, 0.f};

    // Per-k structure: the wave-uniform branch fences load hoisting (R7/R8
    // showed removing it causes catastrophic spill).
#pragma unroll
    for (int k = 0; k < K * K; ++k) {
        const int ky = k / K - 1;
        const int kx = k % K - 1;
        const int r0 = ky + 1;

        const u32x4 oyu = bl128(orsrc, hwB, (2 * k)     * HWc * 4);
        const u32x4 oxu = bl128(orsrc, hwB, (2 * k + 1) * HWc * 4);

        // validity: f in [0,1) <=> bits < 0x3F800000u (neg/NaN/Inf/>=1 larger)
        const unsigned vk = umax2(umax2(umax2(oyu.x, oyu.y), umax2(oyu.z, oyu.w)),
                                  umax2(umax2(oxu.x, oxu.y), umax2(oxu.z, oxu.w)));

        if (__all(vk < 0x3F800000u)) {
            // FAST (wave-uniform): floor(y)=h+ky, floor(x)=w+j+kx; ly=oy, lx=ox.
#pragma unroll
            for (int j = 0; j < 4; ++j) {
                const int   c  = j + kx + 1;   // static after unroll
                const float oy = elem(oyu, j);
                const float ox = elem(oxu, j);
                const float tp = win[r0][c]     + ox * (win[r0][c + 1]     - win[r0][c]);
                const float bo = win[r0 + 1][c] + ox * (win[r0 + 1][c + 1] - win[r0 + 1][c]);
                acc[j] += wgt[k] * (tp + oy * (bo - tp));   // wgt[k]: uniform s_load
            }
        } else {
            // GENERAL (never taken for this data; keeps arbitrary-offset correctness)
#pragma unroll
            for (int j = 0; j < 4; ++j) {
                const float y = (float)(h + ky)     + elem(oyu, j);
                const float x = (float)(w + j + kx) + elem(oxu, j);
                const float y0f = floorf(y), x0f = floorf(x);
                const float ly = y - y0f,  lx = x - x0f;
                const int y0 = (int)y0f, x0 = (int)x0f;

                const int cb = ((y0 << 9) + x0) * 4;
                float v00 = bl32(irsrc, cb,              0);
                float v01 = bl32(irsrc, cb + 4,          0);
                float v10 = bl32(irsrc, cb + Wc * 4,     0);
                float v11 = bl32(irsrc, cb + Wc * 4 + 4, 0);
                const bool vx0 = (unsigned)x0       < (unsigned)Wc;
                const bool vx1 = (unsigned)(x0 + 1) < (unsigned)Wc;
                v00 = vx0 ? v00 : 0.f;   v10 = vx0 ? v10 : 0.f;
                v01 = vx1 ? v01 : 0.f;   v11 = vx1 ? v11 : 0.f;

                const float top = v00 + lx * (v01 - v00);
                const float bot = v10 + lx * (v11 - v10);
                acc[j] += wgt[k] * (top + ly * (bot - top));
            }
        }
    }

    float4 o;
    o.x = acc[0]; o.y = acc[1]; o.z = acc[2]; o.w = acc[3];
    *reinterpret_cast<float4*>(out + (size_t)b * HWc + hw) = o;
}

extern "C" void kernel_launch(void* const* d_in, const int* in_sizes, int n_in,
                              void* d_out, int out_size, void* d_ws, size_t ws_size,
                              hipStream_t stream)
{
    const float* inp = (const float*)d_in[0];   // (8,512,512)
    const float* wgt = (const float*)d_in[1];   // (1,1,3,3) = 9 floats
    const float* off = (const float*)d_in[2];   // (8,18,512,512)
    float* out = (float*)d_out;

    const int grid = Bc * (Hc / 2);             // 2048 blocks, 1024 px each

    deform_conv2d_kernel<<<grid, 256, 0, stream>>>(inp, wgt, off, out);
}

// Round 14
// 33.773 us; speedup vs baseline: 1.0554x; 1.0554x over previous
//
#include <hip/hip_runtime.h>

constexpr int K  = 3;
constexpr int Hc = 512, Wc = 512, Bc = 8;
constexpr int HWc = Hc * Wc;

typedef __attribute__((ext_vector_type(2))) unsigned int u32x2;
typedef __attribute__((ext_vector_type(4))) unsigned int u32x4;

__device__ __forceinline__ float bl32(__amdgpu_buffer_rsrc_t r, int vo, int so) {
    return __uint_as_float(__builtin_amdgcn_raw_buffer_load_b32(r, vo, so, 0));
}
__device__ __forceinline__ u32x2 bl64(__amdgpu_buffer_rsrc_t r, int vo, int so) {
    return __builtin_amdgcn_raw_buffer_load_b64(r, vo, so, 0);
}
__device__ __forceinline__ u32x4 bl128(__amdgpu_buffer_rsrc_t r, int vo, int so) {
    return __builtin_amdgcn_raw_buffer_load_b128(r, vo, so, 0);
}

__global__ __launch_bounds__(256, 6) void deform_conv2d_kernel(
    const float* __restrict__ inp,     // (B,H,W)
    const float* __restrict__ wgt,     // (K*K)
    const float* __restrict__ off,     // (B, 2*K*K, H, W)
    float* __restrict__ out)           // (B,H,W)
{
    const int idx = blockIdx.x * blockDim.x + threadIdx.x;   // 4 pixels per thread
    const int p4  = idx << 2;
    const int b   = p4 >> 18;            // / (512*512)
    const int hw  = p4 & (HWc - 1);
    const int h   = hw >> 9;
    const int w   = hw & (Wc - 1);       // multiple of 4

    __amdgpu_buffer_rsrc_t orsrc = __builtin_amdgcn_make_buffer_rsrc(
        (void*)(off + (size_t)b * (2 * K * K) * HWc), (short)0,
        (2 * K * K) * HWc * 4, 0x00020000);
    __amdgpu_buffer_rsrc_t irsrc = __builtin_amdgcn_make_buffer_rsrc(
        (void*)(inp + (size_t)b * HWc), (short)0, HWc * 4, 0x00020000);

    float wk[K * K];
#pragma unroll
    for (int k = 0; k < K * K; ++k) wk[k] = wgt[k];   // wave-uniform s_loads

    // ---- shared 4x7 window: rows h-1..h+2, cols w-1..w+5 (zero-padded) ----
    // Row OOB handled free by SRD bounds check (flat index wraps OOB -> 0).
    // Column wrap-aliasing fixed by 3 masks.
    const int  fbB = ((h - 1) * Wc + (w - 1)) * 4;
    const bool m0 = (w >= 1);
    const bool m5 = (w + 4 < Wc);
    const bool m6 = (w + 5 < Wc);

    float win[4][7];
#pragma unroll
    for (int r = 0; r < 4; ++r) {
        const int rb = fbB + r * Wc * 4;
        const float e0 = bl32 (irsrc, rb,      0);   // col w-1
        const u32x4 md = bl128(irsrc, rb + 4,  0);   // cols w..w+3 (16B aligned)
        const u32x2 e5 = bl64 (irsrc, rb + 20, 0);   // cols w+4,w+5 (8B aligned)
        win[r][0] = m0 ? e0 : 0.f;
        win[r][1] = __uint_as_float(md.x);
        win[r][2] = __uint_as_float(md.y);
        win[r][3] = __uint_as_float(md.z);
        win[r][4] = __uint_as_float(md.w);
        win[r][5] = m5 ? __uint_as_float(e5.x) : 0.f;
        win[r][6] = m6 ? __uint_as_float(e5.y) : 0.f;
    }

    const int hwB = hw * 4;
    float acc[4] = {0.f, 0.f, 0.f, 0.f};

    // Per-k structure: the wave-uniform branch doubles as a scheduling fence --
    // it stops the compiler from hoisting all 18 offset loads (the R7/R8
    // catastrophic-spill mode), keeping liveness under the (256,6) cap.
#pragma unroll
    for (int k = 0; k < K * K; ++k) {
        const int ky = k / K - 1;
        const int kx = k % K - 1;

        const u32x4 oyu = bl128(orsrc, hwB, (2 * k)     * HWc * 4);
        const u32x4 oxu = bl128(orsrc, hwB, (2 * k + 1) * HWc * 4);
        const float oya[4] = {__uint_as_float(oyu.x), __uint_as_float(oyu.y),
                              __uint_as_float(oyu.z), __uint_as_float(oyu.w)};
        const float oxa[4] = {__uint_as_float(oxu.x), __uint_as_float(oxu.y),
                              __uint_as_float(oxu.z), __uint_as_float(oxu.w)};

        const float mn = fminf(fminf(fminf(oya[0], oya[1]), fminf(oya[2], oya[3])),
                               fminf(fminf(oxa[0], oxa[1]), fminf(oxa[2], oxa[3])));
        const float mx = fmaxf(fmaxf(fmaxf(oya[0], oya[1]), fmaxf(oya[2], oya[3])),
                               fmaxf(fmaxf(oxa[0], oxa[1]), fmaxf(oxa[2], oxa[3])));

        if (__all((mn >= 0.f) && (mx < 1.f))) {
            // FAST (wave-uniform): floor(y)=h+ky, floor(x)=w+j+kx; ly=oy, lx=ox.
            const int r0 = ky + 1;
#pragma unroll
            for (int j = 0; j < 4; ++j) {
                const int c = j + kx + 1;   // window col of x0; static after unroll
                const float t  = win[r0][c]     + oxa[j] * (win[r0][c + 1]     - win[r0][c]);
                const float bo = win[r0 + 1][c] + oxa[j] * (win[r0 + 1][c + 1] - win[r0 + 1][c]);
                acc[j] += wk[k] * (t + oya[j] * (bo - t));
            }
        } else {
            // GENERAL (never taken for this data; keeps arbitrary-offset correctness)
#pragma unroll
            for (int j = 0; j < 4; ++j) {
                const float y = (float)(h + ky)     + oya[j];
                const float x = (float)(w + j + kx) + oxa[j];
                const float y0f = floorf(y), x0f = floorf(x);
                const float ly = y - y0f,  lx = x - x0f;
                const int y0 = (int)y0f, x0 = (int)x0f;

                const int cb = ((y0 << 9) + x0) * 4;
                float v00 = bl32(irsrc, cb,              0);
                float v01 = bl32(irsrc, cb + 4,          0);
                float v10 = bl32(irsrc, cb + Wc * 4,     0);
                float v11 = bl32(irsrc, cb + Wc * 4 + 4, 0);
                const bool vx0 = (unsigned)x0       < (unsigned)Wc;
                const bool vx1 = (unsigned)(x0 + 1) < (unsigned)Wc;
                v00 = vx0 ? v00 : 0.f;   v10 = vx0 ? v10 : 0.f;
                v01 = vx1 ? v01 : 0.f;   v11 = vx1 ? v11 : 0.f;

                const float top = v00 + lx * (v01 - v00);
                const float bot = v10 + lx * (v11 - v10);
                acc[j] += wk[k] * (top + ly * (bot - top));
            }
        }
    }

    float4 o;
    o.x = acc[0]; o.y = acc[1]; o.z = acc[2]; o.w = acc[3];
    *reinterpret_cast<float4*>(out + p4) = o;    // 16B aligned, coalesced
}

extern "C" void kernel_launch(void* const* d_in, const int* in_sizes, int n_in,
                              void* d_out, int out_size, void* d_ws, size_t ws_size,
                              hipStream_t stream)
{
    const float* inp = (const float*)d_in[0];   // (8,512,512)
    const float* wgt = (const float*)d_in[1];   // (1,1,3,3) = 9 floats
    const float* off = (const float*)d_in[2];   // (8,18,512,512)
    float* out = (float*)d_out;

    const int nthreads = Bc * HWc / 4;          // 4 px per thread
    const int block = 256;
    const int grid  = nthreads / block;         // 2048

    deform_conv2d_kernel<<<grid, block, 0, stream>>>(inp, wgt, off, out);
}